// Round 3
// baseline (211.471 us; speedup 1.0000x reference)
//
#include <hip/hip_runtime.h>

// YOLO-style loss on MI355X — round 3.
// pred:      [B, 8, 8, 8] f32   (B = 65536)
// label_rc:  [B, L, 2]    i32   (L = 16)
// label_box: [B, L, 3]    f32
// out:       [1] f32 = (coord + cond) / B
//
// R3: algebraic split. noobj = sum_all - sum_labeled(dedup).
//  Part A (blocks >= nbB): pure streaming float4 reduction over pred
//    (every float4 .w is a p3 or p7). No cross-lane, no labels -> fill rate.
//  Part B (blocks < nbB): 4 batches/wave, 16 label-lanes each. Gathers the
//    responsible cell's 32B directly from global (L2/L3-warm), computes
//    coord/conf, subtracts labeled-cell noobj once per distinct cell via
//    per-wave LDS atomicMin owner election. No ds_bpermute anywhere.
//  Both write block partials to d_ws; 1-block reduce kernel finishes.

static constexpr float LAMBDA_COORD = 5.0f;
static constexpr float LAMBDA_NOOBJ = 0.5f;
static constexpr float EPS_F = 1e-9f;

__device__ __forceinline__ float bbox_iou(float px, float py, float pr,
                                          float gx, float gy, float gr) {
    float l1 = px - pr, r1 = px + pr, t1 = py - pr, b1 = py + pr;
    float l2 = gx - gr, r2 = gx + gr, t2 = gy - gr, b2 = gy + gr;
    float iw = fmaxf(fminf(r1, r2) - fmaxf(l1, l2), 0.0f);
    float ih = fmaxf(fminf(b1, b2) - fmaxf(t1, t2), 0.0f);
    float inter = iw * ih;
    float a1 = (r1 - l1) * (b1 - t1);
    float a2 = (r2 - l2) * (b2 - t2);
    return inter / (a1 + a2 - inter + EPS_F);
}

__global__ __launch_bounds__(256) void yolo_loss_fused(
    const float* __restrict__ pred,
    const int*   __restrict__ label_rc,
    const float* __restrict__ label_box,
    float* __restrict__ partials,
    int B, int L, int nbB, int nbA)
{
    const int lane    = threadIdx.x & 63;
    const int wave_ib = threadIdx.x >> 6;     // 0..3

    __shared__ unsigned int owner[4][256];    // [wave][sub*64 + cell]
    __shared__ float wsum[4];

    float acc = 0.0f;

    if ((int)blockIdx.x < nbB) {
        // ================= Part B: labels =================
        const int sub = lane >> 4;            // batch within wave (0..3)
        const int ll  = lane & 15;            // label within batch
        const int wave_id = blockIdx.x * 4 + wave_ib;
        const int b = wave_id * 4 + sub;

        // init owner election table (all 64 lanes, 4 entries each)
        #pragma unroll
        for (int k = 0; k < 4; ++k)
            owner[wave_ib][k * 64 + lane] = 0xFFFFFFFFu;

        const bool active = (b < B) && (ll < L);
        int   cell = 0;
        float gx = 0.f, gy = 0.f, gr = 0.f;
        float4 g0 = make_float4(0.f, 0.f, 0.f, 0.f);
        float4 g1 = g0;

        if (active) {
            const int2 rc = *(const int2*)(label_rc + ((size_t)b * L + ll) * 2);
            cell = rc.x * 8 + rc.y;
            const float* lb = label_box + ((size_t)b * L + ll) * 3;
            gx = lb[0]; gy = lb[1]; gr = lb[2];
            const float4* gp =
                (const float4*)(pred + ((size_t)b << 9) + ((size_t)cell << 3));
            g0 = gp[0];                        // p0..p3
            g1 = gp[1];                        // p4..p7
            atomicMin(&owner[wave_ib][sub * 64 + cell], (unsigned)ll);
        }

        if (active) {
            const float p0 = g0.x, p1 = g0.y, p2 = g0.z, p3 = g0.w;
            const float p4 = g1.x, p5 = g1.y, p6 = g1.z, p7 = g1.w;

            float iou1 = bbox_iou(p0, p1, p2, gx, gy, gr);
            float iou2 = bbox_iou(p4, p5, p6, gx, gy, gr);
            bool  sw   = iou2 > iou1;
            float cx      = sw ? p4 : p0;
            float cy      = sw ? p5 : p1;
            float cr      = sw ? p6 : p2;
            float conf    = sw ? p7 : p3;
            float un_conf = sw ? p3 : p7;
            float bigger  = sw ? iou2 : iou1;
            float smaller = sw ? iou1 : iou2;
            float dx = cx - gx, dy = cy - gy, dr = cr - gr;
            acc += LAMBDA_COORD * (dx * dx + dy * dy + dr * dr);
            float d1 = bigger - conf;
            float d2 = smaller - un_conf;
            acc += d1 * d1 + LAMBDA_NOOBJ * (d2 * d2);

            // subtract this cell's noobj contribution exactly once
            if (owner[wave_ib][sub * 64 + cell] == (unsigned)ll)
                acc -= LAMBDA_NOOBJ * (p3 * p3 + p7 * p7);
        }
    } else {
        // ================= Part A: streaming noobj sum =================
        const int aBlock = (int)blockIdx.x - nbB;
        const float4* pv = (const float4*)pred;
        const size_t N4 = (size_t)B * 128;           // B*G*G*C/4
        const size_t stride = (size_t)nbA * 256;
        size_t i = (size_t)aBlock * 256 + threadIdx.x;

        float a0 = 0.f, a1 = 0.f, a2 = 0.f, a3 = 0.f;
        for (; i + 3 * stride < N4; i += 4 * stride) {
            float w0 = pv[i].w;
            float w1 = pv[i + stride].w;
            float w2 = pv[i + 2 * stride].w;
            float w3 = pv[i + 3 * stride].w;
            a0 += w0 * w0; a1 += w1 * w1; a2 += w2 * w2; a3 += w3 * w3;
        }
        for (; i < N4; i += stride) {
            float w = pv[i].w; a0 += w * w;
        }
        acc = LAMBDA_NOOBJ * ((a0 + a1) + (a2 + a3));
    }

    // ---- wave reduction ----
    #pragma unroll
    for (int off = 32; off > 0; off >>= 1)
        acc += __shfl_xor(acc, off);

    // ---- block reduction -> one partial per block ----
    if (lane == 0) wsum[wave_ib] = acc;
    __syncthreads();
    if (threadIdx.x == 0)
        partials[blockIdx.x] = wsum[0] + wsum[1] + wsum[2] + wsum[3];
}

__global__ __launch_bounds__(256) void reduce_kernel(
    const float* __restrict__ partials, float* __restrict__ out,
    int n4, float invB)
{
    const float4* p4 = (const float4*)partials;
    float4 s4 = make_float4(0.f, 0.f, 0.f, 0.f);
    for (int i = threadIdx.x; i < n4; i += 256) {
        float4 v = p4[i];
        s4.x += v.x; s4.y += v.y; s4.z += v.z; s4.w += v.w;
    }
    float s = (s4.x + s4.y) + (s4.z + s4.w);
    #pragma unroll
    for (int off = 32; off > 0; off >>= 1)
        s += __shfl_xor(s, off);

    __shared__ float wsum[4];
    const int lane = threadIdx.x & 63, w = threadIdx.x >> 6;
    if (lane == 0) wsum[w] = s;
    __syncthreads();
    if (threadIdx.x == 0)
        out[0] = (wsum[0] + wsum[1] + wsum[2] + wsum[3]) * invB;
}

extern "C" void kernel_launch(void* const* d_in, const int* in_sizes, int n_in,
                              void* d_out, int out_size, void* d_ws, size_t ws_size,
                              hipStream_t stream) {
    const float* pred      = (const float*)d_in[0];
    const int*   label_rc  = (const int*)d_in[1];
    const float* label_box = (const float*)d_in[2];
    float*       out       = (float*)d_out;
    float*       partials  = (float*)d_ws;

    const int B = in_sizes[0] / 512;          // G*G*C = 8*8*8
    const int L = in_sizes[1] / (B * 2);      // labels per batch (16)
    const float invB = 1.0f / (float)B;

    const int nbB = (B + 15) / 16;            // 16 batches per block (4/wave x 4 waves)
    const int nbA = 8192;                     // streaming blocks
    const int total = nbB + nbA;              // 12288, multiple of 4

    yolo_loss_fused<<<total, 256, 0, stream>>>(
        pred, label_rc, label_box, partials, B, L, nbB, nbA);

    reduce_kernel<<<1, 256, 0, stream>>>(partials, out, total / 4, invB);
}

// Round 4
// 205.422 us; speedup vs baseline: 1.0294x; 1.0294x over previous
//
#include <hip/hip_runtime.h>

// YOLO-style loss on MI355X — round 4.
// pred:      [B, 8, 8, 8] f32   (B = 65536)
// label_rc:  [B, L, 2]    i32   (L = 16)
// label_box: [B, L, 3]    f32
// out:       [1] f32 = (coord + cond) / B
//
// R4: block-local fusion. Each block owns W=16 consecutive batches:
//   1. Stream the slice's 32 KB of pred (float4, fully coalesced) through
//      registers into LDS, accumulating lambda_noobj * w^2 on the fly
//      (every float4 .w is a p3 or p7).
//   2. Barrier; each of the 256 threads resolves one (batch,label) pair,
//      gathering the responsible cell's 8 floats FROM LDS (no second HBM
//      fetch, no random HBM access — R3's mistake).
//   3. obj-mask dedup via per-(batch,cell) LDS atomicMin owner election;
//      the owning thread subtracts that cell's noobj term once.
// HBM traffic = pred 128 MiB + labels 20 MiB, each exactly once, coalesced.

static constexpr float LAMBDA_COORD = 5.0f;
static constexpr float LAMBDA_NOOBJ = 0.5f;
static constexpr float EPS_F = 1e-9f;

__device__ __forceinline__ float bbox_iou(float px, float py, float pr,
                                          float gx, float gy, float gr) {
    float l1 = px - pr, r1 = px + pr, t1 = py - pr, b1 = py + pr;
    float l2 = gx - gr, r2 = gx + gr, t2 = gy - gr, b2 = gy + gr;
    float iw = fmaxf(fminf(r1, r2) - fmaxf(l1, l2), 0.0f);
    float ih = fmaxf(fminf(b1, b2) - fmaxf(t1, t2), 0.0f);
    float inter = iw * ih;
    float a1 = (r1 - l1) * (b1 - t1);
    float a2 = (r2 - l2) * (b2 - t2);
    return inter / (a1 + a2 - inter + EPS_F);
}

#define W_BATCH 16   // batches per block; W_BATCH * 512 floats = 32 KB LDS

__global__ __launch_bounds__(256) void yolo_loss_kernel(
    const float* __restrict__ pred,
    const int*   __restrict__ label_rc,
    const float* __restrict__ label_box,
    float* __restrict__ partials,
    int B, int L)
{
    __shared__ float        sp[W_BATCH * 512];   // staged pred slice (32 KB)
    __shared__ unsigned int owner[W_BATCH * 64]; // dedup table (4 KB)
    __shared__ float        wsum[4];

    const int tid = threadIdx.x;
    const int b0  = blockIdx.x * W_BATCH;
    const int nb  = min(W_BATCH, B - b0);        // batches in this block

    // init owner table (256 threads x 4 entries)
    #pragma unroll
    for (int k = 0; k < 4; ++k)
        owner[k * 256 + tid] = 0xFFFFFFFFu;

    // ---- phase 1: stream pred slice -> LDS, accumulate noobj sum ----
    const float4* gp = (const float4*)(pred + (size_t)b0 * 512);
    float4*       sv = (float4*)sp;
    const int     n4 = nb * 128;                 // float4s in slice

    float acc = 0.0f;
    if (nb == W_BATCH) {                         // fast path: full slice
        float4 v[8];
        #pragma unroll
        for (int k = 0; k < 8; ++k) v[k] = gp[k * 256 + tid];
        #pragma unroll
        for (int k = 0; k < 8; ++k) {
            acc += v[k].w * v[k].w;
            sv[k * 256 + tid] = v[k];
        }
    } else {
        for (int i = tid; i < n4; i += 256) {
            float4 v = gp[i];
            acc += v.w * v.w;
            sv[i] = v;
        }
    }
    acc *= LAMBDA_NOOBJ;
    __syncthreads();

    // ---- phase 2: one (batch,label) pair per thread, gather from LDS ----
    int   cell = -1, w = 0;
    float p3 = 0.f, p7 = 0.f;
    if (tid < nb * L) {
        w = tid / L;
        const int l = tid - w * L;
        const int b = b0 + w;

        const int2 rc = *(const int2*)(label_rc + ((size_t)b * L + l) * 2);
        cell = rc.x * 8 + rc.y;
        atomicMin(&owner[w * 64 + cell], (unsigned)tid);

        const float* lb = label_box + ((size_t)b * L + l) * 3;
        const float gx = lb[0], gy = lb[1], gr = lb[2];

        const float4* cp = (const float4*)(sp + w * 512 + cell * 8);
        const float4 c0 = cp[0];
        const float4 c1 = cp[1];
        const float p0 = c0.x, p1 = c0.y, p2 = c0.z;
        const float p4 = c1.x, p5 = c1.y, p6 = c1.z;
        p3 = c0.w; p7 = c1.w;

        float iou1 = bbox_iou(p0, p1, p2, gx, gy, gr);
        float iou2 = bbox_iou(p4, p5, p6, gx, gy, gr);
        bool  sw   = iou2 > iou1;
        float cx      = sw ? p4 : p0;
        float cy      = sw ? p5 : p1;
        float cr      = sw ? p6 : p2;
        float conf    = sw ? p7 : p3;
        float un_conf = sw ? p3 : p7;
        float bigger  = sw ? iou2 : iou1;
        float smaller = sw ? iou1 : iou2;
        float dx = cx - gx, dy = cy - gy, dr = cr - gr;
        acc += LAMBDA_COORD * (dx * dx + dy * dy + dr * dr);
        float d1 = bigger - conf;
        float d2 = smaller - un_conf;
        acc += d1 * d1 + LAMBDA_NOOBJ * (d2 * d2);
    }
    __syncthreads();

    // ---- phase 3: owner thread subtracts the labeled cell's noobj once ----
    if (cell >= 0 && owner[w * 64 + cell] == (unsigned)tid)
        acc -= LAMBDA_NOOBJ * (p3 * p3 + p7 * p7);

    // ---- block reduction -> one partial per block ----
    #pragma unroll
    for (int off = 32; off > 0; off >>= 1)
        acc += __shfl_xor(acc, off);
    const int lane = tid & 63, wv = tid >> 6;
    if (lane == 0) wsum[wv] = acc;
    __syncthreads();
    if (tid == 0)
        partials[blockIdx.x] = wsum[0] + wsum[1] + wsum[2] + wsum[3];
}

__global__ __launch_bounds__(256) void reduce_kernel(
    const float* __restrict__ partials, float* __restrict__ out,
    int n, float invB)
{
    float s = 0.0f;
    for (int i = threadIdx.x; i < n; i += 256)
        s += partials[i];
    #pragma unroll
    for (int off = 32; off > 0; off >>= 1)
        s += __shfl_xor(s, off);

    __shared__ float wsum[4];
    const int lane = threadIdx.x & 63, w = threadIdx.x >> 6;
    if (lane == 0) wsum[w] = s;
    __syncthreads();
    if (threadIdx.x == 0)
        out[0] = (wsum[0] + wsum[1] + wsum[2] + wsum[3]) * invB;
}

extern "C" void kernel_launch(void* const* d_in, const int* in_sizes, int n_in,
                              void* d_out, int out_size, void* d_ws, size_t ws_size,
                              hipStream_t stream) {
    const float* pred      = (const float*)d_in[0];
    const int*   label_rc  = (const int*)d_in[1];
    const float* label_box = (const float*)d_in[2];
    float*       out       = (float*)d_out;
    float*       partials  = (float*)d_ws;

    const int B = in_sizes[0] / 512;          // G*G*C = 8*8*8
    const int L = in_sizes[1] / (B * 2);      // labels per batch (16)
    const float invB = 1.0f / (float)B;

    const int blocks = (B + W_BATCH - 1) / W_BATCH;   // 4096
    yolo_loss_kernel<<<blocks, 256, 0, stream>>>(
        pred, label_rc, label_box, partials, B, L);

    reduce_kernel<<<1, 256, 0, stream>>>(partials, out, blocks, invB);
}